// Round 17
// baseline (114.241 us; speedup 1.0000x reference)
//
#include <hip/hip_runtime.h>
#include <hip/hip_bf16.h>
#include <hip/hip_fp8.h>

#define FDIM 256
#define K2   512
#define DNB  32
#define TM   32
#define NMAX 100000
#define CONVB 2048

typedef __attribute__((ext_vector_type(8))) short bf16x8;
typedef __attribute__((ext_vector_type(4))) float f32x4;
typedef __attribute__((ext_vector_type(2))) float f32x2;
typedef __attribute__((ext_vector_type(4))) unsigned int u32x4;
typedef __attribute__((ext_vector_type(2))) unsigned int u32x2;

// Fallback scratch in BSS (used only if ws_size is too small).
__device__ __align__(16) unsigned char g_FDb[(size_t)NMAX * FDIM];   // fp8 table
__device__ float g_degb[NMAX];
// Small combined-weight arrays (L2-resident, read-heavy).
__device__ __align__(16) unsigned short g_Wc[FDIM * K2];   // [o][k] bf16
__device__ float g_c2[FDIM];
__device__ float g_c3[FDIM];

__device__ __forceinline__ unsigned short f2bf(float f) {
    __hip_bfloat16 h = __float2bfloat16(f);
    return *reinterpret_cast<unsigned short*>(&h);
}

// fp8 e4m3 pack/unpack (HW cvt when available; round-trip self-consistent)
__device__ __forceinline__ unsigned int enc4(float a, float b, float c, float d) {
#if __has_builtin(__builtin_amdgcn_cvt_pk_fp8_f32)
    int w = 0;
    w = __builtin_amdgcn_cvt_pk_fp8_f32(a, b, w, false);
    w = __builtin_amdgcn_cvt_pk_fp8_f32(c, d, w, true);
    return (unsigned int)w;
#else
    __hip_fp8_e4m3 ha(a), hb(b), hc(c), hd(d);
    return (unsigned)ha.__x | ((unsigned)hb.__x << 8) |
           ((unsigned)hc.__x << 16) | ((unsigned)hd.__x << 24);
#endif
}
__device__ __forceinline__ f32x4 dec4(unsigned int w) {
#if __has_builtin(__builtin_amdgcn_cvt_pk_f32_fp8)
    f32x2 lo = __builtin_amdgcn_cvt_pk_f32_fp8((int)w, false);
    f32x2 hi = __builtin_amdgcn_cvt_pk_f32_fp8((int)w, true);
    return (f32x4){lo.x, lo.y, hi.x, hi.y};
#else
    __hip_fp8_e4m3 h0, h1, h2, h3;
    h0.__x = (unsigned char)(w);
    h1.__x = (unsigned char)(w >> 8);
    h2.__x = (unsigned char)(w >> 16);
    h3.__x = (unsigned char)(w >> 24);
    return (f32x4){(float)h0, (float)h1, (float)h2, (float)h3};
#endif
}

// ---------- 1) build_prep (R16-validated): NT loads + regular stores; fp8 table ----------
__global__ __launch_bounds__(256) void build_prep(
    const float* __restrict__ fd,
    const float* __restrict__ feats,
    const float* __restrict__ W1,
    const float* __restrict__ W2,
    const float* __restrict__ b1,
    const float* __restrict__ b2,
    float Dmul, int N,
    unsigned char* tab_p, float* deg_p)
{
    unsigned char* tab = tab_p ? tab_p : g_FDb;
    float* deg = deg_p ? deg_p : g_degb;
    int bid = blockIdx.x;
    int tid = threadIdx.x;

    if (bid >= 256) {
        size_t tidg = (size_t)(bid - 256) * 256 + tid;
        size_t nthr = (size_t)CONVB * 256;
        size_t total16 = (size_t)N * (FDIM / 16);
        const f32x4* in4 = (const f32x4*)fd;
        u32x4* out16 = (u32x4*)tab;

        size_t i = tidg;
        for (; i + nthr < total16; i += 2 * nthr) {
            f32x4 a0 = __builtin_nontemporal_load(in4 + 4 * i);
            f32x4 a1 = __builtin_nontemporal_load(in4 + 4 * i + 1);
            f32x4 a2 = __builtin_nontemporal_load(in4 + 4 * i + 2);
            f32x4 a3 = __builtin_nontemporal_load(in4 + 4 * i + 3);
            size_t j = i + nthr;
            f32x4 b0 = __builtin_nontemporal_load(in4 + 4 * j);
            f32x4 b1v = __builtin_nontemporal_load(in4 + 4 * j + 1);
            f32x4 b2v = __builtin_nontemporal_load(in4 + 4 * j + 2);
            f32x4 b3 = __builtin_nontemporal_load(in4 + 4 * j + 3);
            u32x4 oa, ob;
            oa.x = enc4(a0.x, a0.y, a0.z, a0.w);
            oa.y = enc4(a1.x, a1.y, a1.z, a1.w);
            oa.z = enc4(a2.x, a2.y, a2.z, a2.w);
            oa.w = enc4(a3.x, a3.y, a3.z, a3.w);
            ob.x = enc4(b0.x, b0.y, b0.z, b0.w);
            ob.y = enc4(b1v.x, b1v.y, b1v.z, b1v.w);
            ob.z = enc4(b2v.x, b2v.y, b2v.z, b2v.w);
            ob.w = enc4(b3.x, b3.y, b3.z, b3.w);
            out16[i] = oa;
            out16[j] = ob;
        }
        for (; i < total16; i += nthr) {
            f32x4 a0 = __builtin_nontemporal_load(in4 + 4 * i);
            f32x4 a1 = __builtin_nontemporal_load(in4 + 4 * i + 1);
            f32x4 a2 = __builtin_nontemporal_load(in4 + 4 * i + 2);
            f32x4 a3 = __builtin_nontemporal_load(in4 + 4 * i + 3);
            u32x4 o;
            o.x = enc4(a0.x, a0.y, a0.z, a0.w);
            o.y = enc4(a1.x, a1.y, a1.z, a1.w);
            o.z = enc4(a2.x, a2.y, a2.z, a2.w);
            o.w = enc4(a3.x, a3.y, a3.z, a3.w);
            out16[i] = o;
        }
        return;
    }

    // ---- weight combine: o = bid
    __shared__ float w2s[FDIM];
    __shared__ float rv[4], ru[4];
    int o = bid;

    for (size_t n = (size_t)o * 256 + tid; n < (size_t)N; n += 65536)
        deg[n] = feats[n * FDIM];

    w2s[tid] = W2[(size_t)o * K2 + FDIM + tid];
    __syncthreads();

    const float* w1a = W1 + tid;           // column k0 = tid       -> C1
    const float* w1b = W1 + FDIM + tid;    // column k1 = 256+tid   -> c2 sum
    float acc0 = 0.f, acc1 = 0.f;
    for (int j = 0; j < FDIM; j += 8) {
        float r0[8], r1[8];
        #pragma unroll
        for (int u = 0; u < 8; ++u) {
            r0[u] = w1a[(size_t)(j + u) * K2];
            r1[u] = w1b[(size_t)(j + u) * K2];
        }
        #pragma unroll
        for (int u = 0; u < 8; ++u) {
            acc0 = fmaf(w2s[j + u], r0[u], acc0);
            acc1 = fmaf(w2s[j + u], r1[u], acc1);
        }
    }
    g_Wc[(size_t)o * K2 + FDIM + tid] = f2bf(acc0);
    g_Wc[(size_t)o * K2 + tid]        = f2bf(W2[(size_t)o * K2 + tid]);

    float v = acc1;
    float u = b1[tid] * w2s[tid];
    #pragma unroll
    for (int s = 32; s; s >>= 1) { v += __shfl_down(v, s); u += __shfl_down(u, s); }
    if ((tid & 63) == 0) { rv[tid >> 6] = v; ru[tid >> 6] = u; }
    __syncthreads();
    if (tid == 0) {
        g_c2[o] = rv[0] + rv[1] + rv[2] + rv[3];
        g_c3[o] = b2[o] + Dmul * (ru[0] + ru[1] + ru[2] + ru[3]);
    }
}

// ---------- 2) gg_norm: fused gather(fp8,warm) -> LDS -> MFMA -> normalize ----------
// 32 rows/block, 8 waves x 4 rows. LDS layout identical to validated R2/gemm_norm.
__global__ __launch_bounds__(512, 4) void gg_norm(
    const unsigned char* tab_p, const float* deg_p,
    const int* __restrict__ adj,
    const int* __restrict__ in1, int B1,
    const int* __restrict__ in2, int B2,
    const int* __restrict__ neg, int total,
    float* __restrict__ out)
{
    const unsigned char* tab = tab_p ? tab_p : g_FDb;
    const float* deg = deg_p ? deg_p : g_degb;

    __shared__ __align__(16) char lds[TM * 1024];   // bf16 [32][512]; reused f32 [32][256]
    __shared__ float Sdeg[TM];

    int tid = threadIdx.x, wave = tid >> 6, lane = tid & 63;
    int half = lane >> 5, l31 = lane & 31;
    int base = blockIdx.x * TM;

    // ---- gather phase: wave w -> rows w*4 .. +3
    #pragma unroll
    for (int i = 0; i < 4; ++i) {
        int row = wave * 4 + i;
        int t = base + row;
        char* rowp = lds + row * 1024;
        int swz = (row & 7) << 4;
        if (t >= total) {
            ushort4 z4 = make_ushort4(0, 0, 0, 0);
            *(ushort4*)(rowp + ((lane * 8) ^ swz)) = z4;
            if (lane < 32) {
                bf16x8 z8 = {0, 0, 0, 0, 0, 0, 0, 0};
                *(bf16x8*)(rowp + 512 + ((l31 * 16) ^ swz)) = z8;
            }
            if (lane == 0) Sdeg[row] = 0.f;
            continue;   // wave-uniform
        }
        int node = (t < B1) ? in1[t] : ((t < B1 + B2) ? in2[t - B1] : neg[t - B1 - B2]);

        int idx = 0; float dg = 0.f;
        if (lane < DNB) {
            idx = adj[(size_t)node * DNB + lane];
            dg = deg[idx];
        }
        #pragma unroll
        for (int s = 16; s; s >>= 1) dg += __shfl_down(dg, s);
        if (lane == 0) Sdeg[row] = dg;

        // NF: 4 fp8/lane -> 4 bf16 (8B) at bytes [0,512) of the row
        unsigned int nw = *(const unsigned int*)(tab + (size_t)node * FDIM + lane * 4);
        f32x4 nf = dec4(nw);
        *(ushort4*)(rowp + ((lane * 8) ^ swz)) =
            make_ushort4(f2bf(nf.x), f2bf(nf.y), f2bf(nf.z), f2bf(nf.w));

        // neighbor sum: half-wave h covers neighbors d+2u+h; lane covers cols l31*8..+7
        float acc[8];
        #pragma unroll
        for (int k = 0; k < 8; ++k) acc[k] = 0.f;
        #pragma unroll
        for (int d = 0; d < DNB; d += 16) {
            u32x2 v[8];
            #pragma unroll
            for (int u = 0; u < 8; ++u) {
                int nb = __shfl(idx, d + u * 2 + half);
                v[u] = *(const u32x2*)(tab + (size_t)nb * FDIM + l31 * 8);
            }
            #pragma unroll
            for (int u = 0; u < 8; ++u) {
                f32x4 lo = dec4(v[u].x);
                f32x4 hi = dec4(v[u].y);
                acc[0] += lo.x; acc[1] += lo.y; acc[2] += lo.z; acc[3] += lo.w;
                acc[4] += hi.x; acc[5] += hi.y; acc[6] += hi.z; acc[7] += hi.w;
            }
        }
        #pragma unroll
        for (int k = 0; k < 8; ++k) acc[k] += __shfl_xor(acc[k], 32);

        if (lane < 32) {
            bf16x8 ah;
            #pragma unroll
            for (int k = 0; k < 8; ++k) ah[k] = (short)f2bf(acc[k]);
            *(bf16x8*)(rowp + 512 + ((l31 * 16) ^ swz)) = ah;   // bytes [512,1024) = k 256..511
        }
    }
    __syncthreads();

    // ---- MFMA: 8 waves, 4 tiles each. wave w: mt = w>>2, cols c0=(w&3)*64
    int l15 = lane & 15, lg = lane >> 4;
    int swzA = (l15 & 7) << 4;
    int mt = wave >> 2;
    int c0 = (wave & 3) * 64;
    f32x4 acc[4];
    #pragma unroll
    for (int nt = 0; nt < 4; ++nt) acc[nt] = (f32x4){0.f, 0.f, 0.f, 0.f};

    const char* pA = lds + (size_t)(mt * 16 + l15) * 1024;
    const unsigned short* wcB = g_Wc + (size_t)(c0 + l15) * K2 + lg * 8;

    #pragma unroll 4
    for (int kk = 0; kk < K2; kk += 32) {
        int kb = kk * 2 + lg * 16;
        bf16x8 a0 = *(const bf16x8*)(pA + (kb ^ swzA));
        #pragma unroll
        for (int nt = 0; nt < 4; ++nt) {
            bf16x8 b = *(const bf16x8*)(wcB + (size_t)nt * 16 * K2 + kk);
            acc[nt] = __builtin_amdgcn_mfma_f32_16x16x32_bf16(a0, b, acc[nt], 0, 0, 0);
        }
    }
    __syncthreads();   // all LDS reads done -> safe to overwrite with f32 stage

    // ---- stage raw acc to LDS as f32 [32][256] (HW-verified D layout)
    float* outf = (float*)lds;
    #pragma unroll
    for (int nt = 0; nt < 4; ++nt)
        #pragma unroll
        for (int r = 0; r < 4; ++r) {
            int row = mt * 16 + lg * 4 + r;
            int col = c0 + nt * 16 + l15;
            outf[row * 256 + col] = acc[nt][r];
        }
    __syncthreads();

    // ---- epilogue: wave w -> rows w*4 .. +3
    float4 c2v = *(const float4*)(g_c2 + lane * 4);
    float4 c3v = *(const float4*)(g_c3 + lane * 4);
    #pragma unroll
    for (int r = 0; r < 4; ++r) {
        int row = wave * 4 + r;
        int t = base + row;
        if (t >= total) break;                   // wave-uniform
        float sd = Sdeg[row];
        float4 v = *(float4*)(outf + row * 256 + lane * 4);
        v.x += sd * c2v.x + c3v.x;
        v.y += sd * c2v.y + c3v.y;
        v.z += sd * c2v.z + c3v.z;
        v.w += sd * c2v.w + c3v.w;
        float ss = v.x * v.x + v.y * v.y + v.z * v.z + v.w * v.w;
        #pragma unroll
        for (int s = 32; s; s >>= 1) ss += __shfl_xor(ss, s);
        float inv = 1.0f / fmaxf(sqrtf(ss), 1e-12f);
        f32x4 o;
        o.x = v.x * inv; o.y = v.y * inv; o.z = v.z * inv; o.w = v.w * inv;
        __builtin_nontemporal_store(o, (f32x4*)(out + (size_t)t * FDIM + lane * 4));
    }
}

extern "C" void kernel_launch(void* const* d_in, const int* in_sizes, int n_in,
                              void* d_out, int out_size, void* d_ws, size_t ws_size,
                              hipStream_t stream) {
    const float* feat_data = (const float*)d_in[0];
    const float* feats     = (const float*)d_in[1];
    const float* W1        = (const float*)d_in[2];
    const float* b1        = (const float*)d_in[3];
    const float* W2        = (const float*)d_in[4];
    const float* b2        = (const float*)d_in[5];
    const int*   adj       = (const int*)d_in[6];
    const int*   in1       = (const int*)d_in[7];
    const int*   in2       = (const int*)d_in[8];
    const int*   neg       = (const int*)d_in[9];

    int B1 = in_sizes[7];
    int B2 = in_sizes[8];
    int Bn = in_sizes[9];
    int N  = in_sizes[0] / FDIM;
    int D  = in_sizes[6] / N;   // == 32

    float* out = (float*)d_out;
    int total = B1 + B2 + Bn;

    // ws layout: [tab fp8 N*256][deg f32 N]
    size_t tab_bytes = (size_t)N * FDIM;
    size_t need = ((tab_bytes + 255) & ~(size_t)255) + (size_t)N * 4;
    bool usews = (ws_size >= need);
    unsigned char* tab = usews ? (unsigned char*)d_ws : nullptr;
    float* deg = usews ? (float*)((char*)d_ws + ((tab_bytes + 255) & ~(size_t)255)) : nullptr;

    build_prep<<<256 + CONVB, 256, 0, stream>>>(feat_data, feats, W1, W2, b1, b2,
                                                (float)D, N, tab, deg);
    gg_norm<<<(total + TM - 1) / TM, 512, 0, stream>>>(tab, deg, adj, in1, B1,
                                                       in2, B2, neg, total, out);
}

// Round 18
// 97.542 us; speedup vs baseline: 1.1712x; 1.1712x over previous
//
#include <hip/hip_runtime.h>
#include <hip/hip_bf16.h>
#include <hip/hip_fp8.h>

#define FDIM 256
#define K2   512
#define DNB  32
#define TM   32
#define NMAX 100000
#define TMAX 20480
#define CONVB 2048

typedef __attribute__((ext_vector_type(8))) short bf16x8;
typedef __attribute__((ext_vector_type(4))) float f32x4;
typedef __attribute__((ext_vector_type(2))) float f32x2;
typedef __attribute__((ext_vector_type(4))) unsigned int u32x4;
typedef __attribute__((ext_vector_type(2))) unsigned int u32x2;

// Fallback scratch in BSS (used only if ws_size is too small).
__device__ __align__(16) unsigned char g_FDb[(size_t)NMAX * FDIM];   // fp8 table
__device__ __align__(16) unsigned char g_Xb[(size_t)TMAX * K2];      // fp8 X rows
__device__ float g_degb[NMAX];
__device__ float g_Sdegb[TMAX];
// Small combined-weight arrays (L2-resident, read-heavy).
__device__ __align__(16) unsigned short g_Wc[FDIM * K2];   // [o][k] bf16
__device__ float g_c2[FDIM];
__device__ float g_c3[FDIM];

__device__ __forceinline__ unsigned short f2bf(float f) {
    __hip_bfloat16 h = __float2bfloat16(f);
    return *reinterpret_cast<unsigned short*>(&h);
}

// fp8 e4m3 pack/unpack (HW cvt when available; round-trip self-consistent)
__device__ __forceinline__ unsigned int enc4(float a, float b, float c, float d) {
#if __has_builtin(__builtin_amdgcn_cvt_pk_fp8_f32)
    int w = 0;
    w = __builtin_amdgcn_cvt_pk_fp8_f32(a, b, w, false);
    w = __builtin_amdgcn_cvt_pk_fp8_f32(c, d, w, true);
    return (unsigned int)w;
#else
    __hip_fp8_e4m3 ha(a), hb(b), hc(c), hd(d);
    return (unsigned)ha.__x | ((unsigned)hb.__x << 8) |
           ((unsigned)hc.__x << 16) | ((unsigned)hd.__x << 24);
#endif
}
__device__ __forceinline__ f32x4 dec4(unsigned int w) {
#if __has_builtin(__builtin_amdgcn_cvt_pk_f32_fp8)
    f32x2 lo = __builtin_amdgcn_cvt_pk_f32_fp8((int)w, false);
    f32x2 hi = __builtin_amdgcn_cvt_pk_f32_fp8((int)w, true);
    return (f32x4){lo.x, lo.y, hi.x, hi.y};
#else
    __hip_fp8_e4m3 h0, h1, h2, h3;
    h0.__x = (unsigned char)(w);
    h1.__x = (unsigned char)(w >> 8);
    h2.__x = (unsigned char)(w >> 16);
    h3.__x = (unsigned char)(w >> 24);
    return (f32x4){(float)h0, (float)h1, (float)h2, (float)h3};
#endif
}

// ---------- 1) build_prep (R16-validated): NT loads + regular stores; fp8 table ----------
__global__ __launch_bounds__(256) void build_prep(
    const float* __restrict__ fd,
    const float* __restrict__ feats,
    const float* __restrict__ W1,
    const float* __restrict__ W2,
    const float* __restrict__ b1,
    const float* __restrict__ b2,
    float Dmul, int N,
    unsigned char* tab_p, float* deg_p)
{
    unsigned char* tab = tab_p ? tab_p : g_FDb;
    float* deg = deg_p ? deg_p : g_degb;
    int bid = blockIdx.x;
    int tid = threadIdx.x;

    if (bid >= 256) {
        size_t tidg = (size_t)(bid - 256) * 256 + tid;
        size_t nthr = (size_t)CONVB * 256;
        size_t total16 = (size_t)N * (FDIM / 16);
        const f32x4* in4 = (const f32x4*)fd;
        u32x4* out16 = (u32x4*)tab;

        size_t i = tidg;
        for (; i + nthr < total16; i += 2 * nthr) {
            f32x4 a0 = __builtin_nontemporal_load(in4 + 4 * i);
            f32x4 a1 = __builtin_nontemporal_load(in4 + 4 * i + 1);
            f32x4 a2 = __builtin_nontemporal_load(in4 + 4 * i + 2);
            f32x4 a3 = __builtin_nontemporal_load(in4 + 4 * i + 3);
            size_t j = i + nthr;
            f32x4 b0 = __builtin_nontemporal_load(in4 + 4 * j);
            f32x4 b1v = __builtin_nontemporal_load(in4 + 4 * j + 1);
            f32x4 b2v = __builtin_nontemporal_load(in4 + 4 * j + 2);
            f32x4 b3 = __builtin_nontemporal_load(in4 + 4 * j + 3);
            u32x4 oa, ob;
            oa.x = enc4(a0.x, a0.y, a0.z, a0.w);
            oa.y = enc4(a1.x, a1.y, a1.z, a1.w);
            oa.z = enc4(a2.x, a2.y, a2.z, a2.w);
            oa.w = enc4(a3.x, a3.y, a3.z, a3.w);
            ob.x = enc4(b0.x, b0.y, b0.z, b0.w);
            ob.y = enc4(b1v.x, b1v.y, b1v.z, b1v.w);
            ob.z = enc4(b2v.x, b2v.y, b2v.z, b2v.w);
            ob.w = enc4(b3.x, b3.y, b3.z, b3.w);
            out16[i] = oa;
            out16[j] = ob;
        }
        for (; i < total16; i += nthr) {
            f32x4 a0 = __builtin_nontemporal_load(in4 + 4 * i);
            f32x4 a1 = __builtin_nontemporal_load(in4 + 4 * i + 1);
            f32x4 a2 = __builtin_nontemporal_load(in4 + 4 * i + 2);
            f32x4 a3 = __builtin_nontemporal_load(in4 + 4 * i + 3);
            u32x4 o;
            o.x = enc4(a0.x, a0.y, a0.z, a0.w);
            o.y = enc4(a1.x, a1.y, a1.z, a1.w);
            o.z = enc4(a2.x, a2.y, a2.z, a2.w);
            o.w = enc4(a3.x, a3.y, a3.z, a3.w);
            out16[i] = o;
        }
        return;
    }

    // ---- weight combine: o = bid
    __shared__ float w2s[FDIM];
    __shared__ float rv[4], ru[4];
    int o = bid;

    for (size_t n = (size_t)o * 256 + tid; n < (size_t)N; n += 65536)
        deg[n] = feats[n * FDIM];

    w2s[tid] = W2[(size_t)o * K2 + FDIM + tid];
    __syncthreads();

    const float* w1a = W1 + tid;           // column k0 = tid       -> C1
    const float* w1b = W1 + FDIM + tid;    // column k1 = 256+tid   -> c2 sum
    float acc0 = 0.f, acc1 = 0.f;
    for (int j = 0; j < FDIM; j += 8) {
        float r0[8], r1[8];
        #pragma unroll
        for (int u = 0; u < 8; ++u) {
            r0[u] = w1a[(size_t)(j + u) * K2];
            r1[u] = w1b[(size_t)(j + u) * K2];
        }
        #pragma unroll
        for (int u = 0; u < 8; ++u) {
            acc0 = fmaf(w2s[j + u], r0[u], acc0);
            acc1 = fmaf(w2s[j + u], r1[u], acc1);
        }
    }
    g_Wc[(size_t)o * K2 + FDIM + tid] = f2bf(acc0);
    g_Wc[(size_t)o * K2 + tid]        = f2bf(W2[(size_t)o * K2 + tid]);

    float v = acc1;
    float u = b1[tid] * w2s[tid];
    #pragma unroll
    for (int s = 32; s; s >>= 1) { v += __shfl_down(v, s); u += __shfl_down(u, s); }
    if ((tid & 63) == 0) { rv[tid >> 6] = v; ru[tid >> 6] = u; }
    __syncthreads();
    if (tid == 0) {
        g_c2[o] = rv[0] + rv[1] + rv[2] + rv[3];
        g_c3[o] = b2[o] + Dmul * (ru[0] + ru[1] + ru[2] + ru[3]);
    }
}

// ---------- 2) gather: fp8 rows, full-depth (16 loads in flight), fp8 X out ----------
__global__ __launch_bounds__(256, 8) void gather(
    const unsigned char* tab_p, const float* deg_p,
    const int* __restrict__ adj,
    const int* __restrict__ in1, int B1,
    const int* __restrict__ in2, int B2,
    const int* __restrict__ neg, int total,
    unsigned char* X_p, float* Sdeg_p)
{
    const unsigned char* tab = tab_p ? tab_p : g_FDb;
    const float* deg = deg_p ? deg_p : g_degb;
    unsigned char* X = X_p ? X_p : g_Xb;
    float* Sdeg = Sdeg_p ? Sdeg_p : g_Sdegb;

    int wave = threadIdx.x >> 6, lane = threadIdx.x & 63;
    int half = lane >> 5, l31 = lane & 31;
    int t = blockIdx.x * 4 + wave;
    if (t >= total) return;
    int node = (t < B1) ? in1[t] : ((t < B1 + B2) ? in2[t - B1] : neg[t - B1 - B2]);

    int idx = 0; float dg = 0.f;
    if (lane < DNB) {
        idx = adj[(size_t)node * DNB + lane];
        dg = deg[idx];
    }
    #pragma unroll
    for (int s = 16; s; s >>= 1) dg += __shfl_down(dg, s);
    if (lane == 0) Sdeg[t] = dg;

    // NF: verbatim fp8 copy (4B/lane = full 256B row per wave)
    unsigned int nw = *(const unsigned int*)(tab + (size_t)node * FDIM + lane * 4);
    *(unsigned int*)(X + (size_t)t * K2 + lane * 4) = nw;

    // neighbor sum: ALL 16 row-loads in flight (half-wave h covers neighbor 2u+h)
    u32x2 v[16];
    #pragma unroll
    for (int u = 0; u < 16; ++u) {
        int nb = __shfl(idx, u * 2 + half);
        v[u] = *(const u32x2*)(tab + (size_t)nb * FDIM + l31 * 8);
    }
    float acc[8];
    #pragma unroll
    for (int k = 0; k < 8; ++k) acc[k] = 0.f;
    #pragma unroll
    for (int u = 0; u < 16; ++u) {
        f32x4 lo = dec4(v[u].x);
        f32x4 hi = dec4(v[u].y);
        acc[0] += lo.x; acc[1] += lo.y; acc[2] += lo.z; acc[3] += lo.w;
        acc[4] += hi.x; acc[5] += hi.y; acc[6] += hi.z; acc[7] += hi.w;
    }
    // combine even/odd-neighbor halves
    #pragma unroll
    for (int k = 0; k < 8; ++k) acc[k] += __shfl_xor(acc[k], 32);

    if (lane < 32) {
        u32x2 o;
        o.x = enc4(acc[0], acc[1], acc[2], acc[3]);
        o.y = enc4(acc[4], acc[5], acc[6], acc[7]);
        *(u32x2*)(X + (size_t)t * K2 + FDIM + l31 * 8) = o;
    }
}

// ---------- 3) gemm_norm: fp8-X staging -> MFMA + degree term + L2 normalize ----------
__global__ __launch_bounds__(256, 4) void gemm_norm(const unsigned char* X_p,
                                                    const float* Sdeg_p,
                                                    float* __restrict__ out, int total)
{
    const unsigned char* X = X_p ? X_p : g_Xb;
    const float* SdegG = Sdeg_p ? Sdeg_p : g_Sdegb;

    __shared__ __align__(16) char lds[TM * 1024];  // bf16 [32][512]; reused f32 [32][256]
    __shared__ float Sdeg[TM];

    int tid = threadIdx.x, wave = tid >> 6, lane = tid & 63;
    int base = blockIdx.x * TM;

    if (tid < TM) {
        int t = base + tid;
        Sdeg[tid] = (t < total) ? SdegG[t] : 0.f;
    }
    // stage X rows: 8B fp8/lane -> decode -> 16B bf16, swizzled LDS writes
    #pragma unroll
    for (int i = 0; i < 8; ++i) {
        int row = wave * 8 + i;
        int t = base + row;
        u32x2 v = (u32x2){0u, 0u};
        if (t < total) v = *(const u32x2*)(X + (size_t)t * K2 + lane * 8);
        f32x4 lo = dec4(v.x);
        f32x4 hi = dec4(v.y);
        bf16x8 h;
        h[0] = (short)f2bf(lo.x); h[1] = (short)f2bf(lo.y);
        h[2] = (short)f2bf(lo.z); h[3] = (short)f2bf(lo.w);
        h[4] = (short)f2bf(hi.x); h[5] = (short)f2bf(hi.y);
        h[6] = (short)f2bf(hi.z); h[7] = (short)f2bf(hi.w);
        *(bf16x8*)(lds + row * 1024 + ((lane * 16) ^ ((row & 7) << 4))) = h;
    }
    __syncthreads();

    int l15 = lane & 15, lg = lane >> 4;
    int swzA = (l15 & 7) << 4;
    f32x4 acc[2][4];
    #pragma unroll
    for (int mt = 0; mt < 2; ++mt)
        #pragma unroll
        for (int nt = 0; nt < 4; ++nt) acc[mt][nt] = (f32x4){0.f, 0.f, 0.f, 0.f};

    const char* pA0 = lds + (size_t)l15 * 1024;
    const char* pA1 = lds + (size_t)(16 + l15) * 1024;
    const unsigned short* wcB = g_Wc + (size_t)(wave * 64 + l15) * K2 + lg * 8;

    #pragma unroll 4
    for (int kk = 0; kk < K2; kk += 32) {
        int kb = kk * 2 + lg * 16;
        bf16x8 a0 = *(const bf16x8*)(pA0 + (kb ^ swzA));
        bf16x8 a1 = *(const bf16x8*)(pA1 + (kb ^ swzA));
        #pragma unroll
        for (int nt = 0; nt < 4; ++nt) {
            bf16x8 b = *(const bf16x8*)(wcB + (size_t)nt * 16 * K2 + kk);
            acc[0][nt] = __builtin_amdgcn_mfma_f32_16x16x32_bf16(a0, b, acc[0][nt], 0, 0, 0);
            acc[1][nt] = __builtin_amdgcn_mfma_f32_16x16x32_bf16(a1, b, acc[1][nt], 0, 0, 0);
        }
    }
    __syncthreads();

    float* outf = (float*)lds;
    #pragma unroll
    for (int mt = 0; mt < 2; ++mt)
        #pragma unroll
        for (int nt = 0; nt < 4; ++nt)
            #pragma unroll
            for (int r = 0; r < 4; ++r) {
                int row = mt * 16 + lg * 4 + r;
                int col = wave * 64 + nt * 16 + l15;
                outf[row * 256 + col] = acc[mt][nt][r];
            }
    __syncthreads();

    float4 c2v = *(const float4*)(g_c2 + lane * 4);
    float4 c3v = *(const float4*)(g_c3 + lane * 4);
    for (int r = 0; r < 8; ++r) {
        int row = wave * 8 + r;
        int t = base + row;
        if (t >= total) break;                   // wave-uniform
        float sd = Sdeg[row];
        float4 v = *(float4*)(outf + row * 256 + lane * 4);
        v.x += sd * c2v.x + c3v.x;
        v.y += sd * c2v.y + c3v.y;
        v.z += sd * c2v.z + c3v.z;
        v.w += sd * c2v.w + c3v.w;
        float ss = v.x * v.x + v.y * v.y + v.z * v.z + v.w * v.w;
        #pragma unroll
        for (int s = 32; s; s >>= 1) ss += __shfl_xor(ss, s);
        float inv = 1.0f / fmaxf(sqrtf(ss), 1e-12f);
        f32x4 o;
        o.x = v.x * inv; o.y = v.y * inv; o.z = v.z * inv; o.w = v.w * inv;
        __builtin_nontemporal_store(o, (f32x4*)(out + (size_t)t * FDIM + lane * 4));
    }
}

extern "C" void kernel_launch(void* const* d_in, const int* in_sizes, int n_in,
                              void* d_out, int out_size, void* d_ws, size_t ws_size,
                              hipStream_t stream) {
    const float* feat_data = (const float*)d_in[0];
    const float* feats     = (const float*)d_in[1];
    const float* W1        = (const float*)d_in[2];
    const float* b1        = (const float*)d_in[3];
    const float* W2        = (const float*)d_in[4];
    const float* b2        = (const float*)d_in[5];
    const int*   adj       = (const int*)d_in[6];
    const int*   in1       = (const int*)d_in[7];
    const int*   in2       = (const int*)d_in[8];
    const int*   neg       = (const int*)d_in[9];

    int B1 = in_sizes[7];
    int B2 = in_sizes[8];
    int Bn = in_sizes[9];
    int N  = in_sizes[0] / FDIM;
    int D  = in_sizes[6] / N;   // == 32

    float* out = (float*)d_out;
    int total = B1 + B2 + Bn;

    // ws layout: [tab fp8 N*256][X fp8 total*512][deg f32 N][Sdeg f32 total]
    size_t off = 0;
    auto take = [&](size_t bytes) { size_t o = off; off = (off + bytes + 255) & ~(size_t)255; return o; };
    size_t tab_o  = take((size_t)N * FDIM);
    size_t x_o    = take((size_t)total * K2);
    size_t deg_o  = take((size_t)N * 4);
    size_t sdeg_o = take((size_t)total * 4);
    bool usews = (ws_size >= off);

    char* wsb = (char*)d_ws;
    unsigned char* tab = usews ? (unsigned char*)(wsb + tab_o) : nullptr;
    unsigned char* X   = usews ? (unsigned char*)(wsb + x_o)   : nullptr;
    float* deg  = usews ? (float*)(wsb + deg_o)  : nullptr;
    float* Sdeg = usews ? (float*)(wsb + sdeg_o) : nullptr;

    build_prep<<<256 + CONVB, 256, 0, stream>>>(feat_data, feats, W1, W2, b1, b2,
                                                (float)D, N, tab, deg);
    gather<<<(total + 3) / 4, 256, 0, stream>>>(tab, deg, adj, in1, B1, in2, B2,
                                                neg, total, X, Sdeg);
    gemm_norm<<<(total + TM - 1) / TM, 256, 0, stream>>>(X, Sdeg, out, total);
}